// Round 6
// baseline (1096.384 us; speedup 1.0000x reference)
//
#include <hip/hip_runtime.h>

// ---------------------------------------------------------------------------
// All four projections in one launch. 4 rows per block, 128 threads.
// CHUNKED=0: Y[((bb*8+h)*L + l)*16 + dd]                      (row layout, V)
// CHUNKED=1: Y[(((bb*8+h)*4 + dd/4)*L + l)*4 + dd%4]   (chunk-major, Q and K)
// ---------------------------------------------------------------------------
__global__ __launch_bounds__(128) void proj_all_kernel(
    const float* __restrict__ q, const float* __restrict__ k,
    const float* __restrict__ v, const float* __restrict__ v2,
    const float* __restrict__ W_Q, const float* __restrict__ b_Q,
    const float* __restrict__ W_K, const float* __restrict__ b_K,
    const float* __restrict__ W_V, const float* __restrict__ b_V,
    const float* __restrict__ W_V2, const float* __restrict__ b_V2,
    float* __restrict__ Qp, float* __restrict__ Kp,
    float* __restrict__ Vp, float* __restrict__ V2p)
{
  __shared__ float xs[4][128];
  int blk = blockIdx.x;
  const float *X, *W, *B; float* Y; int L, chunked, rb;
  if (blk < 1024)      { X = q;  W = W_Q;  B = b_Q;  Y = Qp;  L = 1024; chunked = 1; rb = blk; }
  else if (blk < 3072) { X = k;  W = W_K;  B = b_K;  Y = Kp;  L = 2048; chunked = 1; rb = blk - 1024; }
  else if (blk < 5120) { X = v;  W = W_V;  B = b_V;  Y = Vp;  L = 2048; chunked = 0; rb = blk - 3072; }
  else                 { X = v2; W = W_V2; B = b_V2; Y = V2p; L = 1024; chunked = 0; rb = blk - 5120; }
  rb *= 4;
  int c = threadIdx.x;
#pragma unroll
  for (int i = 0; i < 4; ++i)
    xs[i][c] = X[(size_t)(rb + i) * 128 + c];
  __syncthreads();
  float b = B[c];
  float a0 = b, a1 = b, a2 = b, a3 = b;
#pragma unroll 8
  for (int d = 0; d < 128; ++d) {
    float w = W[d * 128 + c];
    a0 = fmaf(xs[0][d], w, a0);
    a1 = fmaf(xs[1][d], w, a1);
    a2 = fmaf(xs[2][d], w, a2);
    a3 = fmaf(xs[3][d], w, a3);
  }
  int h = c >> 4, dd = c & 15;
  float av[4] = { a0, a1, a2, a3 };
#pragma unroll
  for (int i = 0; i < 4; ++i) {
    int row = rb + i;
    int bb = row / L;
    int l  = row - bb * L;
    if (chunked)
      Y[(((size_t)(bb * 8 + h) * 4 + (dd >> 2)) * L + l) * 4 + (dd & 3)] = av[i];
    else
      Y[((size_t)(bb * 8 + h) * L + l) * 16 + dd] = av[i];
  }
}

// Guarded hybrid root step for f(u-shifted) = S2 - 1 over current support:
// exact segment root when discriminant real, else Newton.
static __device__ __forceinline__ float hstep(float f, float s1, float cnt)
{
  float arg = fmaf(-cnt, f, s1 * s1);
  return (arg > 0.f) ? f / (s1 + sqrtf(arg)) : f / (2.f * s1);
}

// ---------------------------------------------------------------------------
// Attention pass (fp32). 512 threads = 8 waves, ONE WAVE PER ROW, 8 rows per
// block sharing bh. The K-panel is staged tile-by-tile (T=512 rows, 32KB,
// chunk-major) into LDS by the whole block: 8x reuse cuts L2 score traffic
// 8.4GB -> ~1GB; the stream then runs from LDS (69 TB/s). 16B-stride
// ds_read_b128 is at the LDS BW floor (64 lanes x 16B = 8 clks).
// The tile buffer is DEAD after the score pass, so the compaction arrays
// (sval/sidx, 24KB) alias it -- guarded by one __syncthreads.
//
// FAST PATH (statistical threshold, verified): one pass gives row max m,
// mean mu, std sig. theta = max(mu + Z*sig, m-1) is a high-probability
// LOWER bound on tau*. Compact survivors {x > theta} directly, run the
// monotone hybrid solver on the compacted set from theta. Iteration 0
// computes the true global f(theta); if f < -1e-6 (theta overshot), or
// count==0 or count>CAP, fall back to full dense solve from m-1.
// Accepted path: tau >= theta, excluded cols contribute exactly 0.
//
// No forced occupancy cap (round-3/4 lesson: min-waves below natural VGPR
// usage => scratch spill => GBs of HBM spill traffic).
// ---------------------------------------------------------------------------
template<int LROW, int LCOL>
__global__ __launch_bounds__(512) void attn_kernel(
    const float* __restrict__ RowM, const float* __restrict__ ColM,
    const float* __restrict__ ValM, float* __restrict__ Aout,
    float* __restrict__ OutWs)
{
  constexpr int J   = LCOL / 64;
  constexpr int T   = 512;                // tile rows staged per step
  constexpr int NT  = LCOL / T;
  constexpr int JT  = T / 64;             // j-groups per tile
  constexpr int CAP = 512;
  constexpr float Z = 1.0f;

  __shared__ __align__(16) char smem[32 * 1024];
  float4*         ldsK  = (float4*)smem;                      // [4][T]
  float*          svalb = (float*)smem;                       // [8][CAP]
  unsigned short* sidxb = (unsigned short*)(smem + 16 * 1024);// [8][CAP]

  int tid  = threadIdx.x;
  int ws   = tid >> 6;                    // wave slot 0..7
  int lane = tid & 63;
  int nrg  = LROW / 8;                    // row-groups per bh
  int bh   = blockIdx.x / nrg;
  int rg   = blockIdx.x - bh * nrg;
  int r    = rg * 8 + ws;                 // this wave's row
  int bb   = bh >> 3, h = bh & 7;

  float qf[16];
  { const float* qb = RowM + (size_t)bh * LROW * 16;   // chunk-major block
#pragma unroll
    for (int d = 0; d < 16; ++d)
      qf[d] = qb[((size_t)(d >> 2) * LROW + r) * 4 + (d & 3)] * 0.125f;
  }

  // -------- scores from LDS-staged K tiles --------
  float x[J];
  const float4* Cb = (const float4*)(ColM + (size_t)bh * LCOL * 16);
  for (int t = 0; t < NT; ++t) {
    __syncthreads();                      // prev tile fully consumed
#pragma unroll
    for (int e = 0; e < 4; ++e)           // stage chunk e rows [t*T, t*T+T)
      ldsK[e * T + tid] = Cb[(size_t)e * LCOL + t * T + tid];
    __syncthreads();
#pragma unroll
    for (int jt = 0; jt < JT; ++jt) {
      int kl = lane + 64 * jt;
      float4 k0 = ldsK[0 * T + kl];
      float4 k1 = ldsK[1 * T + kl];
      float4 k2 = ldsK[2 * T + kl];
      float4 k3 = ldsK[3 * T + kl];
      float s = qf[0] * k0.x;
      s = fmaf(qf[1],  k0.y, s); s = fmaf(qf[2],  k0.z, s); s = fmaf(qf[3],  k0.w, s);
      s = fmaf(qf[4],  k1.x, s); s = fmaf(qf[5],  k1.y, s);
      s = fmaf(qf[6],  k1.z, s); s = fmaf(qf[7],  k1.w, s);
      s = fmaf(qf[8],  k2.x, s); s = fmaf(qf[9],  k2.y, s);
      s = fmaf(qf[10], k2.z, s); s = fmaf(qf[11], k2.w, s);
      s = fmaf(qf[12], k3.x, s); s = fmaf(qf[13], k3.y, s);
      s = fmaf(qf[14], k3.z, s); s = fmaf(qf[15], k3.w, s);
      x[t * JT + jt] = s;
    }
  }
  __syncthreads();   // ldsK dead from here; sval/sidx may alias it

  // -------- one-pass stats: max, sum, sumsq --------
  float m = -1e30f, sr = 0.f, qr = 0.f;
#pragma unroll
  for (int j = 0; j < J; ++j) {
    m = fmaxf(m, x[j]);
    sr += x[j];
    qr = fmaf(x[j], x[j], qr);
  }
#pragma unroll
  for (int off = 32; off >= 1; off >>= 1) {
    m  = fmaxf(m, __shfl_xor(m, off));
    sr += __shfl_xor(sr, off);
    qr += __shfl_xor(qr, off);
  }
  float mu  = sr * (1.f / (float)LCOL);
  float sig = sqrtf(fmaxf(qr * (1.f / (float)LCOL) - mu * mu, 0.f));
  float theta = fmaxf(fmaf(Z, sig, mu), m - 1.0f);

  float* arow = Aout + ((size_t)bh * LROW + r) * LCOL;
  const float* Vb = ValM + (size_t)bh * LCOL * 16;
  float* op = OutWs + ((size_t)bb * LROW + r) * 128 + h * 16;

  // -------- survivor count + compaction at theta --------
  int c = 0;
#pragma unroll
  for (int j = 0; j < J; ++j) c += (x[j] > theta) ? 1 : 0;
  int i = c;
#pragma unroll
  for (int off = 1; off <= 32; off <<= 1) {
    int t = __shfl_up(i, off);
    if (lane >= off) i += t;
  }
  int base = i - c;
  int tot  = __shfl(i, 63);

  float* sval = svalb + ws * CAP;
  unsigned short* sidx = sidxb + ws * CAP;

  if (tot >= 1 && tot <= CAP) {
    int w = 0;
#pragma unroll
    for (int j = 0; j < J; ++j) {
      if (x[j] > theta) {
        sval[base + w] = x[j];
        sidx[base + w] = (unsigned short)(lane + 64 * j);
        ++w;
      }
    }
    __threadfence_block();   // wave-local LDS visibility across lanes

    // -------- compacted monotone solver from theta, validity-checked ----
    float tau = theta;
    bool valid = true;
    for (int it = 0; it < 24; ++it) {
      float s1 = 0.f, s2 = 0.f;
      int cnt = 0;
      for (int i2 = lane; i2 < tot; i2 += 64) {
        float t = sval[i2] - tau, r0 = fmaxf(t, 0.f);
        s1 += r0; s2 = fmaf(r0, r0, s2);
        cnt += __popcll(__ballot(t > 0.f));
      }
#pragma unroll
      for (int off = 32; off >= 1; off >>= 1) {
        s1 += __shfl_xor(s1, off);
        s2 += __shfl_xor(s2, off);
      }
      float f = s2 - 1.0f;
      if (it == 0 && f < -1e-6f) { valid = false; break; }  // theta > tau*
      if (f > 1e-6f && s1 > 1e-12f) tau += hstep(f, s1, (float)cnt);
      else break;                                           // converged
    }

    if (valid) {
      // -------- dense A write from live score registers (coalesced) ----
#pragma unroll
      for (int j = 0; j < J; ++j) {
        int kk = lane + 64 * j;
        float t = fmaxf(x[j] - tau, 0.f);
        arow[kk] = t * t;
      }

      // -------- sparse P@V over survivors --------
      float acc[16];
#pragma unroll
      for (int d = 0; d < 16; ++d) acc[d] = 0.f;
      for (int i2 = lane; i2 < tot; i2 += 64) {
        float t = sval[i2] - tau;
        if (t > 0.f) {
          float p = t * t;
          int kk = sidx[i2];
          const float4* vp = (const float4*)(Vb + (size_t)kk * 16);
          float4 v0 = vp[0], v1 = vp[1], v2 = vp[2], v3 = vp[3];
          acc[0]  = fmaf(p, v0.x, acc[0]);  acc[1]  = fmaf(p, v0.y, acc[1]);
          acc[2]  = fmaf(p, v0.z, acc[2]);  acc[3]  = fmaf(p, v0.w, acc[3]);
          acc[4]  = fmaf(p, v1.x, acc[4]);  acc[5]  = fmaf(p, v1.y, acc[5]);
          acc[6]  = fmaf(p, v1.z, acc[6]);  acc[7]  = fmaf(p, v1.w, acc[7]);
          acc[8]  = fmaf(p, v2.x, acc[8]);  acc[9]  = fmaf(p, v2.y, acc[9]);
          acc[10] = fmaf(p, v2.z, acc[10]); acc[11] = fmaf(p, v2.w, acc[11]);
          acc[12] = fmaf(p, v3.x, acc[12]); acc[13] = fmaf(p, v3.y, acc[13]);
          acc[14] = fmaf(p, v3.z, acc[14]); acc[15] = fmaf(p, v3.w, acc[15]);
        }
      }
#pragma unroll
      for (int off = 32; off >= 1; off >>= 1)
#pragma unroll
        for (int d = 0; d < 16; ++d) acc[d] += __shfl_xor(acc[d], off);
      float vv = acc[0];
#pragma unroll
      for (int d = 1; d < 16; ++d)
        vv = (lane == d) ? acc[d] : vv;
      if (lane < 16) op[lane] = vv;
      return;
    }
  }

  // ============ FALLBACK (rare): full dense solve from m-1 ==============
  float tau = m - 1.0f;
  bool done = false;
  for (int it = 0; it < 24; ++it) {
    float a1 = 0.f, a2 = 0.f;
    int ac = 0;
#pragma unroll
    for (int j = 0; j < J; ++j) {
      float t = x[j] - tau, r0 = fmaxf(t, 0.f);
      a1 += r0; a2 = fmaf(r0, r0, a2);
      ac += __popcll(__ballot(t > 0.f));
    }
#pragma unroll
    for (int off = 32; off >= 1; off >>= 1) {
      a1 += __shfl_xor(a1, off);
      a2 += __shfl_xor(a2, off);
    }
    float f = a2 - 1.0f;
    bool g = !done && (f > 1e-6f) && (a1 > 1e-12f);
    if (g) tau += hstep(f, a1, (float)ac); else done = true;
    if (done) break;
  }

  float acc[16];
#pragma unroll
  for (int d = 0; d < 16; ++d) acc[d] = 0.f;
#pragma unroll
  for (int j = 0; j < J; ++j) {
    int kk = lane + 64 * j;
    float t = fmaxf(x[j] - tau, 0.f), p = t * t;
    arow[kk] = p;
    const float4* vp = (const float4*)(Vb + (size_t)kk * 16);
    float4 v0 = vp[0], v1 = vp[1], v2 = vp[2], v3 = vp[3];
    acc[0]  = fmaf(p, v0.x, acc[0]);  acc[1]  = fmaf(p, v0.y, acc[1]);
    acc[2]  = fmaf(p, v0.z, acc[2]);  acc[3]  = fmaf(p, v0.w, acc[3]);
    acc[4]  = fmaf(p, v1.x, acc[4]);  acc[5]  = fmaf(p, v1.y, acc[5]);
    acc[6]  = fmaf(p, v1.z, acc[6]);  acc[7]  = fmaf(p, v1.w, acc[7]);
    acc[8]  = fmaf(p, v2.x, acc[8]);  acc[9]  = fmaf(p, v2.y, acc[9]);
    acc[10] = fmaf(p, v2.z, acc[10]); acc[11] = fmaf(p, v2.w, acc[11]);
    acc[12] = fmaf(p, v3.x, acc[12]); acc[13] = fmaf(p, v3.y, acc[13]);
    acc[14] = fmaf(p, v3.z, acc[14]); acc[15] = fmaf(p, v3.w, acc[15]);
  }
#pragma unroll
  for (int off = 32; off >= 1; off >>= 1)
#pragma unroll
    for (int d = 0; d < 16; ++d) acc[d] += __shfl_xor(acc[d], off);
  float vv = acc[0];
#pragma unroll
  for (int d = 1; d < 16; ++d)
    vv = (lane == d) ? acc[d] : vv;
  if (lane < 16) op[lane] = vv;
}

// ---------------------------------------------------------------------------
// Fused: Y = X1 @ W1 + bias + X2 @ W2, then LayerNorm(gamma,beta) + ReLU.
// 4 rows per block, 128 threads (one output column each, 2 waves).
// ---------------------------------------------------------------------------
__global__ __launch_bounds__(128) void combine_ln_kernel(
    const float* __restrict__ X1, const float* __restrict__ X2,
    const float* __restrict__ W1, const float* __restrict__ W2,
    const float* __restrict__ bias, const float* __restrict__ gamma,
    const float* __restrict__ beta, float* __restrict__ O)
{
  __shared__ float x1s[4][128], x2s[4][128];
  __shared__ float red[2][8];
  int rb = blockIdx.x * 4;
  int c  = threadIdx.x;
#pragma unroll
  for (int i = 0; i < 4; ++i) {
    x1s[i][c] = X1[(size_t)(rb + i) * 128 + c];
    x2s[i][c] = X2[(size_t)(rb + i) * 128 + c];
  }
  __syncthreads();
  float b = bias[c];
  float a0 = b, a1 = b, a2 = b, a3 = b;
#pragma unroll 8
  for (int d = 0; d < 128; ++d) {
    float w1 = W1[d * 128 + c];
    float w2 = W2[d * 128 + c];
    a0 = fmaf(x1s[0][d], w1, fmaf(x2s[0][d], w2, a0));
    a1 = fmaf(x1s[1][d], w1, fmaf(x2s[1][d], w2, a1));
    a2 = fmaf(x1s[2][d], w1, fmaf(x2s[2][d], w2, a2));
    a3 = fmaf(x1s[3][d], w1, fmaf(x2s[3][d], w2, a3));
  }
  float s0 = a0, s1 = a1, s2 = a2, s3 = a3;
  float q0 = a0 * a0, q1 = a1 * a1, q2 = a2 * a2, q3 = a3 * a3;
#pragma unroll
  for (int off = 32; off >= 1; off >>= 1) {
    s0 += __shfl_xor(s0, off); q0 += __shfl_xor(q0, off);
    s1 += __shfl_xor(s1, off); q1 += __shfl_xor(q1, off);
    s2 += __shfl_xor(s2, off); q2 += __shfl_xor(q2, off);
    s3 += __shfl_xor(s3, off); q3 += __shfl_xor(q3, off);
  }
  int wv = c >> 6;
  if ((c & 63) == 0) {
    red[wv][0] = s0; red[wv][1] = q0; red[wv][2] = s1; red[wv][3] = q1;
    red[wv][4] = s2; red[wv][5] = q2; red[wv][6] = s3; red[wv][7] = q3;
  }
  __syncthreads();
  float S0 = red[0][0] + red[1][0], Q0 = red[0][1] + red[1][1];
  float S1 = red[0][2] + red[1][2], Q1 = red[0][3] + red[1][3];
  float S2 = red[0][4] + red[1][4], Q2 = red[0][5] + red[1][5];
  float S3 = red[0][6] + red[1][6], Q3 = red[0][7] + red[1][7];
  float g = gamma[c], be = beta[c];
  float mu, var, rs;
  mu = S0 * (1.f / 128.f); var = fmaxf(Q0 * (1.f / 128.f) - mu * mu, 0.f);
  rs = rsqrtf(var + 1e-5f);
  O[(size_t)(rb + 0) * 128 + c] = fmaxf(fmaf((a0 - mu) * rs, g, be), 0.f);
  mu = S1 * (1.f / 128.f); var = fmaxf(Q1 * (1.f / 128.f) - mu * mu, 0.f);
  rs = rsqrtf(var + 1e-5f);
  O[(size_t)(rb + 1) * 128 + c] = fmaxf(fmaf((a1 - mu) * rs, g, be), 0.f);
  mu = S2 * (1.f / 128.f); var = fmaxf(Q2 * (1.f / 128.f) - mu * mu, 0.f);
  rs = rsqrtf(var + 1e-5f);
  O[(size_t)(rb + 2) * 128 + c] = fmaxf(fmaf((a2 - mu) * rs, g, be), 0.f);
  mu = S3 * (1.f / 128.f); var = fmaxf(Q3 * (1.f / 128.f) - mu * mu, 0.f);
  rs = rsqrtf(var + 1e-5f);
  O[(size_t)(rb + 3) * 128 + c] = fmaxf(fmaf((a3 - mu) * rs, g, be), 0.f);
}

// ---------------------------------------------------------------------------
extern "C"
__attribute__((visibility("default"), used))
void kernel_launch(void* const* d_in, const int* in_sizes, int n_in,
                   void* d_out, int out_size, void* d_ws, size_t ws_size,
                   hipStream_t stream)
{
  (void)in_sizes; (void)n_in; (void)out_size; (void)ws_size;
  const float* q     = (const float*)d_in[0];
  const float* k     = (const float*)d_in[1];
  const float* v     = (const float*)d_in[2];
  const float* v2    = (const float*)d_in[3];
  const float* W_Q   = (const float*)d_in[4];
  const float* b_Q   = (const float*)d_in[5];
  const float* W_K   = (const float*)d_in[6];
  const float* b_K   = (const float*)d_in[7];
  const float* W_V   = (const float*)d_in[8];
  const float* b_V   = (const float*)d_in[9];
  const float* W_V2  = (const float*)d_in[10];
  const float* b_V2  = (const float*)d_in[11];
  const float* W_O   = (const float*)d_in[12];
  const float* b_O   = (const float*)d_in[13];
  const float* W_O2  = (const float*)d_in[14];
  const float* b_O2  = (const float*)d_in[15];
  const float* W_R   = (const float*)d_in[16];
  const float* W_R2  = (const float*)d_in[17];
  const float* gamma = (const float*)d_in[18];
  const float* beta  = (const float*)d_in[19];

  char* ws = (char*)d_ws;
  const size_t MB = 1u << 20;
  float* Qp    = (float*)(ws + 0);        // chunk-major [bh][4][1024][4]
  float* Kp    = (float*)(ws + 2 * MB);   // chunk-major [bh][4][2048][4]
  float* Vp    = (float*)(ws + 6 * MB);   // row-major   [bh][2048][16]
  float* V2p   = (float*)(ws + 10 * MB);  // row-major   [bh][1024][16]
  float* outm1 = (float*)(ws + 12 * MB);
  float* outm2 = (float*)(ws + 14 * MB);

  float* out1  = (float*)d_out;              // (4,1024,128)
  float* out2  = out1 + (size_t)524288;      // (4,2048,128)
  float* Aout  = out1 + (size_t)1572864;     // (4,8,1024,2048)
  float* A2out = out1 + (size_t)68681728;    // (4,8,2048,1024)

  proj_all_kernel<<<6144, 128, 0, stream>>>(
      q, k, v, v2, W_Q, b_Q, W_K, b_K, W_V, b_V, W_V2, b_V2,
      Qp, Kp, Vp, V2p);

  attn_kernel<1024, 2048><<<4096, 512, 0, stream>>>(Qp, Kp, Vp,  Aout,  outm1);
  attn_kernel<2048, 1024><<<8192, 512, 0, stream>>>(Kp, Qp, V2p, A2out, outm2);

  combine_ln_kernel<<<1024, 128, 0, stream>>>(outm1, q, W_O,  W_R,  b_O,
                                              gamma, beta, out1);
  combine_ln_kernel<<<2048, 128, 0, stream>>>(outm2, k, W_O2, W_R2, b_O2,
                                              gamma, beta, out2);
}

// Round 7
// 1096.079 us; speedup vs baseline: 1.0003x; 1.0003x over previous
//
#include <hip/hip_runtime.h>

// ===========================================================================
// DPP wave64 reductions (VALU pipe, ~4-8cyc/step) replacing __shfl_xor
// butterflies (ds_swizzle, ~35-120cyc/step). rocPRIM-style inclusive scan:
// row_shr 1/2/4/8 (row-local prefix), bcast15 row_mask 0xa, bcast31 row_mask
// 0xc. Lane 63 holds the wave total; readlane(63) -> SGPR broadcast.
// ===========================================================================
__device__ __forceinline__ float dpp_scan_add(float x)
{
  x += __int_as_float(__builtin_amdgcn_update_dpp(0, __float_as_int(x), 0x111, 0xf, 0xf, true));
  x += __int_as_float(__builtin_amdgcn_update_dpp(0, __float_as_int(x), 0x112, 0xf, 0xf, true));
  x += __int_as_float(__builtin_amdgcn_update_dpp(0, __float_as_int(x), 0x114, 0xf, 0xf, true));
  x += __int_as_float(__builtin_amdgcn_update_dpp(0, __float_as_int(x), 0x118, 0xf, 0xf, true));
  x += __int_as_float(__builtin_amdgcn_update_dpp(0, __float_as_int(x), 0x142, 0xa, 0xf, true));
  x += __int_as_float(__builtin_amdgcn_update_dpp(0, __float_as_int(x), 0x143, 0xc, 0xf, true));
  return x;                       // inclusive prefix; lane63 = total
}
__device__ __forceinline__ int dpp_scan_add_i(int x)
{
  x += __builtin_amdgcn_update_dpp(0, x, 0x111, 0xf, 0xf, true);
  x += __builtin_amdgcn_update_dpp(0, x, 0x112, 0xf, 0xf, true);
  x += __builtin_amdgcn_update_dpp(0, x, 0x114, 0xf, 0xf, true);
  x += __builtin_amdgcn_update_dpp(0, x, 0x118, 0xf, 0xf, true);
  x += __builtin_amdgcn_update_dpp(0, x, 0x142, 0xa, 0xf, true);
  x += __builtin_amdgcn_update_dpp(0, x, 0x143, 0xc, 0xf, true);
  return x;
}
__device__ __forceinline__ float wave_bcast63(float x)
{
  return __int_as_float(__builtin_amdgcn_readlane(__float_as_int(x), 63));
}
__device__ __forceinline__ float wave_sum(float x)
{
  return wave_bcast63(dpp_scan_add(x));
}
__device__ __forceinline__ float wave_max(float x)
{
  // bound_ctrl=false with old=x: invalid/unmasked lanes keep x (no-op fmax)
  x = fmaxf(x, __int_as_float(__builtin_amdgcn_update_dpp(__float_as_int(x), __float_as_int(x), 0x111, 0xf, 0xf, false)));
  x = fmaxf(x, __int_as_float(__builtin_amdgcn_update_dpp(__float_as_int(x), __float_as_int(x), 0x112, 0xf, 0xf, false)));
  x = fmaxf(x, __int_as_float(__builtin_amdgcn_update_dpp(__float_as_int(x), __float_as_int(x), 0x114, 0xf, 0xf, false)));
  x = fmaxf(x, __int_as_float(__builtin_amdgcn_update_dpp(__float_as_int(x), __float_as_int(x), 0x118, 0xf, 0xf, false)));
  x = fmaxf(x, __int_as_float(__builtin_amdgcn_update_dpp(__float_as_int(x), __float_as_int(x), 0x142, 0xa, 0xf, false)));
  x = fmaxf(x, __int_as_float(__builtin_amdgcn_update_dpp(__float_as_int(x), __float_as_int(x), 0x143, 0xc, 0xf, false)));
  return wave_bcast63(x);
}

// ---------------------------------------------------------------------------
// All four projections in one launch. 4 rows per block, 128 threads.
// CHUNKED=0: Y[((bb*8+h)*L + l)*16 + dd]                      (row layout, V)
// CHUNKED=1: Y[(((bb*8+h)*4 + dd/4)*L + l)*4 + dd%4]   (chunk-major, Q and K)
// ---------------------------------------------------------------------------
__global__ __launch_bounds__(128) void proj_all_kernel(
    const float* __restrict__ q, const float* __restrict__ k,
    const float* __restrict__ v, const float* __restrict__ v2,
    const float* __restrict__ W_Q, const float* __restrict__ b_Q,
    const float* __restrict__ W_K, const float* __restrict__ b_K,
    const float* __restrict__ W_V, const float* __restrict__ b_V,
    const float* __restrict__ W_V2, const float* __restrict__ b_V2,
    float* __restrict__ Qp, float* __restrict__ Kp,
    float* __restrict__ Vp, float* __restrict__ V2p)
{
  __shared__ float xs[4][128];
  int blk = blockIdx.x;
  const float *X, *W, *B; float* Y; int L, chunked, rb;
  if (blk < 1024)      { X = q;  W = W_Q;  B = b_Q;  Y = Qp;  L = 1024; chunked = 1; rb = blk; }
  else if (blk < 3072) { X = k;  W = W_K;  B = b_K;  Y = Kp;  L = 2048; chunked = 1; rb = blk - 1024; }
  else if (blk < 5120) { X = v;  W = W_V;  B = b_V;  Y = Vp;  L = 2048; chunked = 0; rb = blk - 3072; }
  else                 { X = v2; W = W_V2; B = b_V2; Y = V2p; L = 1024; chunked = 0; rb = blk - 5120; }
  rb *= 4;
  int c = threadIdx.x;
#pragma unroll
  for (int i = 0; i < 4; ++i)
    xs[i][c] = X[(size_t)(rb + i) * 128 + c];
  __syncthreads();
  float b = B[c];
  float a0 = b, a1 = b, a2 = b, a3 = b;
#pragma unroll 8
  for (int d = 0; d < 128; ++d) {
    float w = W[d * 128 + c];
    a0 = fmaf(xs[0][d], w, a0);
    a1 = fmaf(xs[1][d], w, a1);
    a2 = fmaf(xs[2][d], w, a2);
    a3 = fmaf(xs[3][d], w, a3);
  }
  int h = c >> 4, dd = c & 15;
  float av[4] = { a0, a1, a2, a3 };
#pragma unroll
  for (int i = 0; i < 4; ++i) {
    int row = rb + i;
    int bb = row / L;
    int l  = row - bb * L;
    if (chunked)
      Y[(((size_t)(bb * 8 + h) * 4 + (dd >> 2)) * L + l) * 4 + (dd & 3)] = av[i];
    else
      Y[((size_t)(bb * 8 + h) * L + l) * 16 + dd] = av[i];
  }
}

// Guarded hybrid root step for f(u-shifted) = S2 - 1 over current support:
// exact segment root when discriminant real, else Newton.
static __device__ __forceinline__ float hstep(float f, float s1, float cnt)
{
  float arg = fmaf(-cnt, f, s1 * s1);
  return (arg > 0.f) ? f / (s1 + sqrtf(arg)) : f / (2.f * s1);
}

// ---------------------------------------------------------------------------
// Attention pass (fp32). ONE WAVE PER ROW, direct L2 score streaming (round-6
// LDS staging was a regression -> L2 BW is not the limit). All cross-lane
// reductions are DPP (VALU pipe) instead of shuffles (LDS pipe): stats,
// compaction prefix-scan, solver sums, final acc reduce. Compacted solver
// registerizes survivors (<=8/lane, statically unrolled, -1e30 sentinels) so
// inner iterations are pure VALU.
//
// FAST PATH (statistical threshold, verified): theta = max(mu + sig, m-1)
// is a high-probability lower bound on tau*. Compact {x > theta} directly;
// run the monotone hybrid solver from theta on the compacted set. Iteration
// 0 computes the true global f(theta); if f < -1e-6 (overshot), or count==0
// or count>CAP, fall back to full dense solve from m-1. Accepted path:
// tau >= theta, excluded cols contribute exactly 0 -> identical math.
//
// No forced occupancy cap (round-3/4: caps below natural VGPR => spills).
// ---------------------------------------------------------------------------
template<int LROW, int LCOL>
__global__ __launch_bounds__(256) void attn_kernel(
    const float* __restrict__ RowM, const float* __restrict__ ColM,
    const float* __restrict__ ValM, float* __restrict__ Aout,
    float* __restrict__ OutWs)
{
  constexpr int J     = LCOL / 64;
  constexpr int CAP   = 512;
  constexpr int SLOTS = CAP / 64;         // survivors per lane (max 8)
  constexpr float Z   = 1.0f;
  __shared__ float          sval[4][CAP];
  __shared__ unsigned short sidx[4][CAP];

  int ws   = threadIdx.x >> 6;                      // wave slot in block
  int wid  = blockIdx.x * 4 + ws;                   // global row id
  int lane = threadIdx.x & 63;
  int bh   = wid / LROW;
  int r    = wid - bh * LROW;
  int bb   = bh >> 3, h = bh & 7;

  float qf[16];
  { const float* qb = RowM + (size_t)bh * LROW * 16;   // chunk-major block
#pragma unroll
    for (int d = 0; d < 16; ++d)
      qf[d] = qb[((size_t)(d >> 2) * LROW + r) * 4 + (d & 3)] * 0.125f;
  }

  // -------- scores (raw) --------
  float x[J];
  const float4* Cb = (const float4*)(ColM + (size_t)bh * LCOL * 16);
#pragma unroll
  for (int j = 0; j < J; ++j) {
    int kk = lane + 64 * j;
    float4 k0 = Cb[0 * LCOL + kk];      // 16B/lane contiguous -> 1KB/wave
    float  s  = qf[0] * k0.x;
    s = fmaf(qf[1], k0.y, s); s = fmaf(qf[2], k0.z, s); s = fmaf(qf[3], k0.w, s);
    float4 k1 = Cb[1 * LCOL + kk];
    s = fmaf(qf[4], k1.x, s); s = fmaf(qf[5], k1.y, s);
    s = fmaf(qf[6], k1.z, s); s = fmaf(qf[7], k1.w, s);
    float4 k2 = Cb[2 * LCOL + kk];
    s = fmaf(qf[8], k2.x, s); s = fmaf(qf[9], k2.y, s);
    s = fmaf(qf[10], k2.z, s); s = fmaf(qf[11], k2.w, s);
    float4 k3 = Cb[3 * LCOL + kk];
    s = fmaf(qf[12], k3.x, s); s = fmaf(qf[13], k3.y, s);
    s = fmaf(qf[14], k3.z, s); s = fmaf(qf[15], k3.w, s);
    x[j] = s;
  }

  // -------- one-pass stats: max, sum, sumsq (DPP reduces) --------
  float ml = -1e30f, sl = 0.f, ql = 0.f;
#pragma unroll
  for (int j = 0; j < J; ++j) {
    ml = fmaxf(ml, x[j]);
    sl += x[j];
    ql = fmaf(x[j], x[j], ql);
  }
  float m  = wave_max(ml);
  float sr = wave_sum(sl);
  float qr = wave_sum(ql);
  float mu  = sr * (1.f / (float)LCOL);
  float sig = sqrtf(fmaxf(qr * (1.f / (float)LCOL) - mu * mu, 0.f));
  float theta = fmaxf(fmaf(Z, sig, mu), m - 1.0f);

  float* arow = Aout + ((size_t)bh * LROW + r) * LCOL;
  const float* Vb = ValM + (size_t)bh * LCOL * 16;
  float* op = OutWs + ((size_t)bb * LROW + r) * 128 + h * 16;

  // -------- survivor count + compaction at theta (DPP prefix scan) ------
  int c = 0;
#pragma unroll
  for (int j = 0; j < J; ++j) c += (x[j] > theta) ? 1 : 0;
  int pre  = dpp_scan_add_i(c);                     // inclusive prefix
  int base = pre - c;
  int tot  = __builtin_amdgcn_readlane(pre, 63);

  if (tot >= 1 && tot <= CAP) {
    int w = 0;
#pragma unroll
    for (int j = 0; j < J; ++j) {
      if (x[j] > theta) {
        sval[ws][base + w] = x[j];
        sidx[ws][base + w] = (unsigned short)(lane + 64 * j);
        ++w;
      }
    }
    __threadfence_block();   // wave-local LDS visibility across lanes

    // -------- registerize survivors (static unroll, sentinel -1e30) -----
    float sv[SLOTS];
    int   iv[SLOTS];
#pragma unroll
    for (int u = 0; u < SLOTS; ++u) {
      int i2 = lane + u * 64;
      bool ok = i2 < tot;
      sv[u] = ok ? sval[ws][i2] : -1e30f;
      iv[u] = ok ? (int)sidx[ws][i2] : 0;
    }

    // -------- compacted monotone solver from theta (pure VALU + DPP) ----
    float tau = theta;
    bool valid = true;
    for (int it = 0; it < 24; ++it) {
      float s1l = 0.f, s2l = 0.f, cml = 0.f;
#pragma unroll
      for (int u = 0; u < SLOTS; ++u) {
        float t = sv[u] - tau, r0 = fmaxf(t, 0.f);
        s1l += r0; s2l = fmaf(r0, r0, s2l);
        cml += (t > 0.f) ? 1.f : 0.f;
      }
      float s1 = dpp_scan_add(s1l);
      float s2 = dpp_scan_add(s2l);
      float cm = dpp_scan_add(cml);
      s1 = wave_bcast63(s1); s2 = wave_bcast63(s2); cm = wave_bcast63(cm);
      float f = s2 - 1.0f;
      if (it == 0 && f < -1e-6f) { valid = false; break; }  // theta > tau*
      if (f > 1e-6f && s1 > 1e-12f) tau += hstep(f, s1, cm);
      else break;                                           // converged
    }

    if (valid) {
      // -------- dense A write from live score registers (coalesced) ----
#pragma unroll
      for (int j = 0; j < J; ++j) {
        int kk = lane + 64 * j;
        float t = fmaxf(x[j] - tau, 0.f);
        arow[kk] = t * t;
      }

      // -------- sparse P@V over register survivors --------
      float acc[16];
#pragma unroll
      for (int d = 0; d < 16; ++d) acc[d] = 0.f;
#pragma unroll
      for (int u = 0; u < SLOTS; ++u) {
        if (sv[u] > tau) {                      // sentinel never passes
          float t = sv[u] - tau;
          float p = t * t;
          const float4* vp = (const float4*)(Vb + (size_t)iv[u] * 16);
          float4 v0 = vp[0], v1 = vp[1], v2 = vp[2], v3 = vp[3];
          acc[0]  = fmaf(p, v0.x, acc[0]);  acc[1]  = fmaf(p, v0.y, acc[1]);
          acc[2]  = fmaf(p, v0.z, acc[2]);  acc[3]  = fmaf(p, v0.w, acc[3]);
          acc[4]  = fmaf(p, v1.x, acc[4]);  acc[5]  = fmaf(p, v1.y, acc[5]);
          acc[6]  = fmaf(p, v1.z, acc[6]);  acc[7]  = fmaf(p, v1.w, acc[7]);
          acc[8]  = fmaf(p, v2.x, acc[8]);  acc[9]  = fmaf(p, v2.y, acc[9]);
          acc[10] = fmaf(p, v2.z, acc[10]); acc[11] = fmaf(p, v2.w, acc[11]);
          acc[12] = fmaf(p, v3.x, acc[12]); acc[13] = fmaf(p, v3.y, acc[13]);
          acc[14] = fmaf(p, v3.z, acc[14]); acc[15] = fmaf(p, v3.w, acc[15]);
        }
      }
      float vv = 0.f;
#pragma unroll
      for (int d = 0; d < 16; ++d) {
        float tt = wave_bcast63(dpp_scan_add(acc[d]));
        vv = (lane == d) ? tt : vv;
      }
      if (lane < 16) op[lane] = vv;
      return;
    }
  }

  // ============ FALLBACK (rare): full dense solve from m-1 ==============
  float tau = m - 1.0f;
  bool done = false;
  for (int it = 0; it < 24; ++it) {
    float a1l = 0.f, a2l = 0.f, acl = 0.f;
#pragma unroll
    for (int j = 0; j < J; ++j) {
      float t = x[j] - tau, r0 = fmaxf(t, 0.f);
      a1l += r0; a2l = fmaf(r0, r0, a2l);
      acl += (t > 0.f) ? 1.f : 0.f;
    }
    float a1 = wave_sum(a1l);
    float a2 = wave_sum(a2l);
    float ac = wave_sum(acl);
    float f = a2 - 1.0f;
    bool g = !done && (f > 1e-6f) && (a1 > 1e-12f);
    if (g) tau += hstep(f, a1, ac); else done = true;
    if (done) break;
  }

  float acc[16];
#pragma unroll
  for (int d = 0; d < 16; ++d) acc[d] = 0.f;
#pragma unroll
  for (int j = 0; j < J; ++j) {
    int kk = lane + 64 * j;
    float t = fmaxf(x[j] - tau, 0.f), p = t * t;
    arow[kk] = p;
    const float4* vp = (const float4*)(Vb + (size_t)kk * 16);
    float4 v0 = vp[0], v1 = vp[1], v2 = vp[2], v3 = vp[3];
    acc[0]  = fmaf(p, v0.x, acc[0]);  acc[1]  = fmaf(p, v0.y, acc[1]);
    acc[2]  = fmaf(p, v0.z, acc[2]);  acc[3]  = fmaf(p, v0.w, acc[3]);
    acc[4]  = fmaf(p, v1.x, acc[4]);  acc[5]  = fmaf(p, v1.y, acc[5]);
    acc[6]  = fmaf(p, v1.z, acc[6]);  acc[7]  = fmaf(p, v1.w, acc[7]);
    acc[8]  = fmaf(p, v2.x, acc[8]);  acc[9]  = fmaf(p, v2.y, acc[9]);
    acc[10] = fmaf(p, v2.z, acc[10]); acc[11] = fmaf(p, v2.w, acc[11]);
    acc[12] = fmaf(p, v3.x, acc[12]); acc[13] = fmaf(p, v3.y, acc[13]);
    acc[14] = fmaf(p, v3.z, acc[14]); acc[15] = fmaf(p, v3.w, acc[15]);
  }
  float vv = 0.f;
#pragma unroll
  for (int d = 0; d < 16; ++d) {
    float tt = wave_bcast63(dpp_scan_add(acc[d]));
    vv = (lane == d) ? tt : vv;
  }
  if (lane < 16) op[lane] = vv;
}

// ---------------------------------------------------------------------------
// Fused: Y = X1 @ W1 + bias + X2 @ W2, then LayerNorm(gamma,beta) + ReLU.
// 4 rows per block, 128 threads (one output column each, 2 waves).
// ---------------------------------------------------------------------------
__global__ __launch_bounds__(128) void combine_ln_kernel(
    const float* __restrict__ X1, const float* __restrict__ X2,
    const float* __restrict__ W1, const float* __restrict__ W2,
    const float* __restrict__ bias, const float* __restrict__ gamma,
    const float* __restrict__ beta, float* __restrict__ O)
{
  __shared__ float x1s[4][128], x2s[4][128];
  __shared__ float red[2][8];
  int rb = blockIdx.x * 4;
  int c  = threadIdx.x;
#pragma unroll
  for (int i = 0; i < 4; ++i) {
    x1s[i][c] = X1[(size_t)(rb + i) * 128 + c];
    x2s[i][c] = X2[(size_t)(rb + i) * 128 + c];
  }
  __syncthreads();
  float b = bias[c];
  float a0 = b, a1 = b, a2 = b, a3 = b;
#pragma unroll 8
  for (int d = 0; d < 128; ++d) {
    float w1 = W1[d * 128 + c];
    float w2 = W2[d * 128 + c];
    a0 = fmaf(x1s[0][d], w1, fmaf(x2s[0][d], w2, a0));
    a1 = fmaf(x1s[1][d], w1, fmaf(x2s[1][d], w2, a1));
    a2 = fmaf(x1s[2][d], w1, fmaf(x2s[2][d], w2, a2));
    a3 = fmaf(x1s[3][d], w1, fmaf(x2s[3][d], w2, a3));
  }
  float s0 = wave_bcast63(dpp_scan_add(a0));
  float q0 = wave_bcast63(dpp_scan_add(a0 * a0));
  float s1 = wave_bcast63(dpp_scan_add(a1));
  float q1 = wave_bcast63(dpp_scan_add(a1 * a1));
  float s2 = wave_bcast63(dpp_scan_add(a2));
  float q2 = wave_bcast63(dpp_scan_add(a2 * a2));
  float s3 = wave_bcast63(dpp_scan_add(a3));
  float q3 = wave_bcast63(dpp_scan_add(a3 * a3));
  int wv = c >> 6;
  if ((c & 63) == 0) {
    red[wv][0] = s0; red[wv][1] = q0; red[wv][2] = s1; red[wv][3] = q1;
    red[wv][4] = s2; red[wv][5] = q2; red[wv][6] = s3; red[wv][7] = q3;
  }
  __syncthreads();
  float S0 = red[0][0] + red[1][0], Q0 = red[0][1] + red[1][1];
  float S1 = red[0][2] + red[1][2], Q1 = red[0][3] + red[1][3];
  float S2 = red[0][4] + red[1][4], Q2 = red[0][5] + red[1][5];
  float S3 = red[0][6] + red[1][6], Q3 = red[0][7] + red[1][7];
  float g = gamma[c], be = beta[c];
  float mu, var, rs;
  mu = S0 * (1.f / 128.f); var = fmaxf(Q0 * (1.f / 128.f) - mu * mu, 0.f);
  rs = rsqrtf(var + 1e-5f);
  O[(size_t)(rb + 0) * 128 + c] = fmaxf(fmaf((a0 - mu) * rs, g, be), 0.f);
  mu = S1 * (1.f / 128.f); var = fmaxf(Q1 * (1.f / 128.f) - mu * mu, 0.f);
  rs = rsqrtf(var + 1e-5f);
  O[(size_t)(rb + 1) * 128 + c] = fmaxf(fmaf((a1 - mu) * rs, g, be), 0.f);
  mu = S2 * (1.f / 128.f); var = fmaxf(Q2 * (1.f / 128.f) - mu * mu, 0.f);
  rs = rsqrtf(var + 1e-5f);
  O[(size_t)(rb + 2) * 128 + c] = fmaxf(fmaf((a2 - mu) * rs, g, be), 0.f);
  mu = S3 * (1.f / 128.f); var = fmaxf(Q3 * (1.f / 128.f) - mu * mu, 0.f);
  rs = rsqrtf(var + 1e-5f);
  O[(size_t)(rb + 3) * 128 + c] = fmaxf(fmaf((a3 - mu) * rs, g, be), 0.f);
}

// ---------------------------------------------------------------------------
extern "C"
__attribute__((visibility("default"), used))
void kernel_launch(void* const* d_in, const int* in_sizes, int n_in,
                   void* d_out, int out_size, void* d_ws, size_t ws_size,
                   hipStream_t stream)
{
  (void)in_sizes; (void)n_in; (void)out_size; (void)ws_size;
  const float* q     = (const float*)d_in[0];
  const float* k     = (const float*)d_in[1];
  const float* v     = (const float*)d_in[2];
  const float* v2    = (const float*)d_in[3];
  const float* W_Q   = (const float*)d_in[4];
  const float* b_Q   = (const float*)d_in[5];
  const float* W_K   = (const float*)d_in[6];
  const float* b_K   = (const float*)d_in[7];
  const float* W_V   = (const float*)d_in[8];
  const float* b_V   = (const float*)d_in[9];
  const float* W_V2  = (const float*)d_in[10];
  const float* b_V2  = (const float*)d_in[11];
  const float* W_O   = (const float*)d_in[12];
  const float* b_O   = (const float*)d_in[13];
  const float* W_O2  = (const float*)d_in[14];
  const float* b_O2  = (const float*)d_in[15];
  const float* W_R   = (const float*)d_in[16];
  const float* W_R2  = (const float*)d_in[17];
  const float* gamma = (const float*)d_in[18];
  const float* beta  = (const float*)d_in[19];

  char* ws = (char*)d_ws;
  const size_t MB = 1u << 20;
  float* Qp    = (float*)(ws + 0);        // chunk-major [bh][4][1024][4]
  float* Kp    = (float*)(ws + 2 * MB);   // chunk-major [bh][4][2048][4]
  float* Vp    = (float*)(ws + 6 * MB);   // row-major   [bh][2048][16]
  float* V2p   = (float*)(ws + 10 * MB);  // row-major   [bh][1024][16]
  float* outm1 = (float*)(ws + 12 * MB);
  float* outm2 = (float*)(ws + 14 * MB);

  float* out1  = (float*)d_out;              // (4,1024,128)
  float* out2  = out1 + (size_t)524288;      // (4,2048,128)
  float* Aout  = out1 + (size_t)1572864;     // (4,8,1024,2048)
  float* A2out = out1 + (size_t)68681728;    // (4,8,2048,1024)

  proj_all_kernel<<<6144, 128, 0, stream>>>(
      q, k, v, v2, W_Q, b_Q, W_K, b_K, W_V, b_V, W_V2, b_V2,
      Qp, Kp, Vp, V2p);

  attn_kernel<1024, 2048><<<8192,  256, 0, stream>>>(Qp, Kp, Vp,  Aout,  outm1);
  attn_kernel<2048, 1024><<<16384, 256, 0, stream>>>(Kp, Qp, V2p, A2out, outm2);

  combine_ln_kernel<<<1024, 128, 0, stream>>>(outm1, q, W_O,  W_R,  b_O,
                                              gamma, beta, out1);
  combine_ln_kernel<<<2048, 128, 0, stream>>>(outm2, k, W_O2, W_R2, b_O2,
                                              gamma, beta, out2);
}

// Round 8
// 1092.692 us; speedup vs baseline: 1.0034x; 1.0031x over previous
//
#include <hip/hip_runtime.h>

// ===========================================================================
// DPP wave64 reductions (VALU pipe) replacing shuffle butterflies (LDS pipe).
// Full-wave inclusive scan: row_shr 1/2/4/8 + bcast15(0xa) + bcast31(0xc);
// lane63 = wave total. Half-wave scan (independent 32-lane halves): drop the
// bcast31 step; lane31 = half0 total, lane63 = half1 total.
// ===========================================================================
__device__ __forceinline__ float dpp_scan_add(float x)
{
  x += __int_as_float(__builtin_amdgcn_update_dpp(0, __float_as_int(x), 0x111, 0xf, 0xf, true));
  x += __int_as_float(__builtin_amdgcn_update_dpp(0, __float_as_int(x), 0x112, 0xf, 0xf, true));
  x += __int_as_float(__builtin_amdgcn_update_dpp(0, __float_as_int(x), 0x114, 0xf, 0xf, true));
  x += __int_as_float(__builtin_amdgcn_update_dpp(0, __float_as_int(x), 0x118, 0xf, 0xf, true));
  x += __int_as_float(__builtin_amdgcn_update_dpp(0, __float_as_int(x), 0x142, 0xa, 0xf, true));
  x += __int_as_float(__builtin_amdgcn_update_dpp(0, __float_as_int(x), 0x143, 0xc, 0xf, true));
  return x;                       // inclusive prefix; lane63 = total
}
__device__ __forceinline__ int dpp_scan_add_i(int x)
{
  x += __builtin_amdgcn_update_dpp(0, x, 0x111, 0xf, 0xf, true);
  x += __builtin_amdgcn_update_dpp(0, x, 0x112, 0xf, 0xf, true);
  x += __builtin_amdgcn_update_dpp(0, x, 0x114, 0xf, 0xf, true);
  x += __builtin_amdgcn_update_dpp(0, x, 0x118, 0xf, 0xf, true);
  x += __builtin_amdgcn_update_dpp(0, x, 0x142, 0xa, 0xf, true);
  x += __builtin_amdgcn_update_dpp(0, x, 0x143, 0xc, 0xf, true);
  return x;
}
__device__ __forceinline__ float dpp_hscan_add(float x)   // 32-lane halves
{
  x += __int_as_float(__builtin_amdgcn_update_dpp(0, __float_as_int(x), 0x111, 0xf, 0xf, true));
  x += __int_as_float(__builtin_amdgcn_update_dpp(0, __float_as_int(x), 0x112, 0xf, 0xf, true));
  x += __int_as_float(__builtin_amdgcn_update_dpp(0, __float_as_int(x), 0x114, 0xf, 0xf, true));
  x += __int_as_float(__builtin_amdgcn_update_dpp(0, __float_as_int(x), 0x118, 0xf, 0xf, true));
  x += __int_as_float(__builtin_amdgcn_update_dpp(0, __float_as_int(x), 0x142, 0xa, 0xf, true));
  return x;                       // lane31 = half0 total, lane63 = half1 total
}
__device__ __forceinline__ float rlf(float x, int l)
{
  return __int_as_float(__builtin_amdgcn_readlane(__float_as_int(x), l));
}
__device__ __forceinline__ float wave_bcast63(float x) { return rlf(x, 63); }
__device__ __forceinline__ float wave_sum(float x) { return wave_bcast63(dpp_scan_add(x)); }
__device__ __forceinline__ float wave_max(float x)
{
  x = fmaxf(x, __int_as_float(__builtin_amdgcn_update_dpp(__float_as_int(x), __float_as_int(x), 0x111, 0xf, 0xf, false)));
  x = fmaxf(x, __int_as_float(__builtin_amdgcn_update_dpp(__float_as_int(x), __float_as_int(x), 0x112, 0xf, 0xf, false)));
  x = fmaxf(x, __int_as_float(__builtin_amdgcn_update_dpp(__float_as_int(x), __float_as_int(x), 0x114, 0xf, 0xf, false)));
  x = fmaxf(x, __int_as_float(__builtin_amdgcn_update_dpp(__float_as_int(x), __float_as_int(x), 0x118, 0xf, 0xf, false)));
  x = fmaxf(x, __int_as_float(__builtin_amdgcn_update_dpp(__float_as_int(x), __float_as_int(x), 0x142, 0xa, 0xf, false)));
  x = fmaxf(x, __int_as_float(__builtin_amdgcn_update_dpp(__float_as_int(x), __float_as_int(x), 0x143, 0xc, 0xf, false)));
  return wave_bcast63(x);
}

// ---------------------------------------------------------------------------
// All four projections in one launch. 4 rows per block, 128 threads.
// CHUNKED=0: Y[((bb*8+h)*L + l)*16 + dd]                      (row layout, V)
// CHUNKED=1: Y[(((bb*8+h)*4 + dd/4)*L + l)*4 + dd%4]   (chunk-major, Q and K)
// ---------------------------------------------------------------------------
__global__ __launch_bounds__(128) void proj_all_kernel(
    const float* __restrict__ q, const float* __restrict__ k,
    const float* __restrict__ v, const float* __restrict__ v2,
    const float* __restrict__ W_Q, const float* __restrict__ b_Q,
    const float* __restrict__ W_K, const float* __restrict__ b_K,
    const float* __restrict__ W_V, const float* __restrict__ b_V,
    const float* __restrict__ W_V2, const float* __restrict__ b_V2,
    float* __restrict__ Qp, float* __restrict__ Kp,
    float* __restrict__ Vp, float* __restrict__ V2p)
{
  __shared__ float xs[4][128];
  int blk = blockIdx.x;
  const float *X, *W, *B; float* Y; int L, chunked, rb;
  if (blk < 1024)      { X = q;  W = W_Q;  B = b_Q;  Y = Qp;  L = 1024; chunked = 1; rb = blk; }
  else if (blk < 3072) { X = k;  W = W_K;  B = b_K;  Y = Kp;  L = 2048; chunked = 1; rb = blk - 1024; }
  else if (blk < 5120) { X = v;  W = W_V;  B = b_V;  Y = Vp;  L = 2048; chunked = 0; rb = blk - 3072; }
  else                 { X = v2; W = W_V2; B = b_V2; Y = V2p; L = 1024; chunked = 0; rb = blk - 5120; }
  rb *= 4;
  int c = threadIdx.x;
#pragma unroll
  for (int i = 0; i < 4; ++i)
    xs[i][c] = X[(size_t)(rb + i) * 128 + c];
  __syncthreads();
  float b = B[c];
  float a0 = b, a1 = b, a2 = b, a3 = b;
#pragma unroll 8
  for (int d = 0; d < 128; ++d) {
    float w = W[d * 128 + c];
    a0 = fmaf(xs[0][d], w, a0);
    a1 = fmaf(xs[1][d], w, a1);
    a2 = fmaf(xs[2][d], w, a2);
    a3 = fmaf(xs[3][d], w, a3);
  }
  int h = c >> 4, dd = c & 15;
  float av[4] = { a0, a1, a2, a3 };
#pragma unroll
  for (int i = 0; i < 4; ++i) {
    int row = rb + i;
    int bb = row / L;
    int l  = row - bb * L;
    if (chunked)
      Y[(((size_t)(bb * 8 + h) * 4 + (dd >> 2)) * L + l) * 4 + (dd & 3)] = av[i];
    else
      Y[((size_t)(bb * 8 + h) * L + l) * 16 + dd] = av[i];
  }
}

// Guarded hybrid root step for f(u-shifted) = S2 - 1 over current support:
// exact segment root when discriminant real, else Newton.
static __device__ __forceinline__ float hstep(float f, float s1, float cnt)
{
  float arg = fmaf(-cnt, f, s1 * s1);
  return (arg > 0.f) ? f / (s1 + sqrtf(arg)) : f / (2.f * s1);
}

// ---------------------------------------------------------------------------
// Attention pass (fp32). TWO ROWS PER WAVE: each K float4 is loaded ONCE and
// used for both rows' dots -> halves L2 score traffic (8.6GB -> 4.3GB) and
// VMEM issue count per row. (R6/R7 falsified LDS-staging and shuffle-latency
// theories; traffic/issue per row is the remaining row-scalable cost.)
// Solver + PV run HALF-WAVE SPLIT (lanes 0-31 own row0, 32-63 own row1) with
// 5-step DPP half-scans. Stats/compaction use full-wave DPP scans.
//
// FAST PATH (statistical threshold, verified): theta = max(mu + sig, m-1)
// is a high-probability lower bound on tau*. Compact {x > theta} directly;
// run the monotone hybrid solver from theta on the compacted set. Iteration
// 0 computes the true global f(theta); if overshoot, or count==0 or
// count>CAP, fall back to full dense solve from m-1 (rare). Accepted path:
// tau >= theta, excluded cols contribute exactly 0 -> identical math.
//
// No forced occupancy cap (round-3/4: caps below natural VGPR => spills).
// ---------------------------------------------------------------------------
template<int LROW, int LCOL>
__global__ __launch_bounds__(256) void attn_kernel(
    const float* __restrict__ RowM, const float* __restrict__ ColM,
    const float* __restrict__ ValM, float* __restrict__ Aout,
    float* __restrict__ OutWs)
{
  constexpr int J   = LCOL / 64;
  constexpr int CAP = 512;
  constexpr float Z = 1.0f;
  __shared__ float          sval[4][2][CAP];
  __shared__ unsigned short sidx[4][2][CAP];

  int ws   = threadIdx.x >> 6;                      // wave slot in block
  int pid  = blockIdx.x * 4 + ws;                   // row-pair id
  int lane = threadIdx.x & 63;
  int half   = lane >> 5;                           // 0 -> row0, 1 -> row1
  int lane31 = lane & 31;
  int bh   = pid / (LROW / 2);
  int pr   = pid - bh * (LROW / 2);
  int row0 = pr * 2;
  int bb   = bh >> 3, h = bh & 7;

  float qf0[16], qf1[16];
  { const float* qb = RowM + (size_t)bh * LROW * 16;   // chunk-major block
#pragma unroll
    for (int d = 0; d < 16; ++d) {
      qf0[d] = qb[((size_t)(d >> 2) * LROW + row0)     * 4 + (d & 3)] * 0.125f;
      qf1[d] = qb[((size_t)(d >> 2) * LROW + row0 + 1) * 4 + (d & 3)] * 0.125f;
    } }

  // -------- scores: each K float4 loaded once, used for both rows --------
  float x0[J], x1[J];
  const float4* Cb = (const float4*)(ColM + (size_t)bh * LCOL * 16);
#pragma unroll
  for (int j = 0; j < J; ++j) {
    int kk = lane + 64 * j;
    float4 k0 = Cb[0 * LCOL + kk];      // 16B/lane contiguous -> 1KB/wave
    float4 k1 = Cb[1 * LCOL + kk];
    float4 k2 = Cb[2 * LCOL + kk];
    float4 k3 = Cb[3 * LCOL + kk];
    float s0, s1;
    s0 = qf0[0] * k0.x;                  s1 = qf1[0] * k0.x;
    s0 = fmaf(qf0[1],  k0.y, s0);        s1 = fmaf(qf1[1],  k0.y, s1);
    s0 = fmaf(qf0[2],  k0.z, s0);        s1 = fmaf(qf1[2],  k0.z, s1);
    s0 = fmaf(qf0[3],  k0.w, s0);        s1 = fmaf(qf1[3],  k0.w, s1);
    s0 = fmaf(qf0[4],  k1.x, s0);        s1 = fmaf(qf1[4],  k1.x, s1);
    s0 = fmaf(qf0[5],  k1.y, s0);        s1 = fmaf(qf1[5],  k1.y, s1);
    s0 = fmaf(qf0[6],  k1.z, s0);        s1 = fmaf(qf1[6],  k1.z, s1);
    s0 = fmaf(qf0[7],  k1.w, s0);        s1 = fmaf(qf1[7],  k1.w, s1);
    s0 = fmaf(qf0[8],  k2.x, s0);        s1 = fmaf(qf1[8],  k2.x, s1);
    s0 = fmaf(qf0[9],  k2.y, s0);        s1 = fmaf(qf1[9],  k2.y, s1);
    s0 = fmaf(qf0[10], k2.z, s0);        s1 = fmaf(qf1[10], k2.z, s1);
    s0 = fmaf(qf0[11], k2.w, s0);        s1 = fmaf(qf1[11], k2.w, s1);
    s0 = fmaf(qf0[12], k3.x, s0);        s1 = fmaf(qf1[12], k3.x, s1);
    s0 = fmaf(qf0[13], k3.y, s0);        s1 = fmaf(qf1[13], k3.y, s1);
    s0 = fmaf(qf0[14], k3.z, s0);        s1 = fmaf(qf1[14], k3.z, s1);
    s0 = fmaf(qf0[15], k3.w, s0);        s1 = fmaf(qf1[15], k3.w, s1);
    x0[j] = s0; x1[j] = s1;
  }

  // -------- one-pass stats per row (full-wave DPP) --------
  float m0l = -1e30f, s0l = 0.f, q0l = 0.f;
  float m1l = -1e30f, s1l = 0.f, q1l = 0.f;
#pragma unroll
  for (int j = 0; j < J; ++j) {
    m0l = fmaxf(m0l, x0[j]); s0l += x0[j]; q0l = fmaf(x0[j], x0[j], q0l);
    m1l = fmaxf(m1l, x1[j]); s1l += x1[j]; q1l = fmaf(x1[j], x1[j], q1l);
  }
  float m0 = wave_max(m0l), sr0 = wave_sum(s0l), qr0 = wave_sum(q0l);
  float m1 = wave_max(m1l), sr1 = wave_sum(s1l), qr1 = wave_sum(q1l);
  float mu0 = sr0 * (1.f / (float)LCOL);
  float mu1 = sr1 * (1.f / (float)LCOL);
  float sg0 = sqrtf(fmaxf(qr0 * (1.f / (float)LCOL) - mu0 * mu0, 0.f));
  float sg1 = sqrtf(fmaxf(qr1 * (1.f / (float)LCOL) - mu1 * mu1, 0.f));
  float th0 = fmaxf(fmaf(Z, sg0, mu0), m0 - 1.0f);
  float th1 = fmaxf(fmaf(Z, sg1, mu1), m1 - 1.0f);

  float* arow = Aout + ((size_t)bh * LROW + row0) * LCOL;
  const float* Vb = ValM + (size_t)bh * LCOL * 16;
  float* op = OutWs + ((size_t)bb * LROW + row0) * 128 + h * 16;

  // -------- survivor counts + compaction at theta (full-wave scans) -----
  int c0 = 0, c1 = 0;
#pragma unroll
  for (int j = 0; j < J; ++j) {
    c0 += (x0[j] > th0) ? 1 : 0;
    c1 += (x1[j] > th1) ? 1 : 0;
  }
  int pre0 = dpp_scan_add_i(c0);
  int pre1 = dpp_scan_add_i(c1);
  int base0 = pre0 - c0, base1 = pre1 - c1;
  int tot0 = __builtin_amdgcn_readlane(pre0, 63);
  int tot1 = __builtin_amdgcn_readlane(pre1, 63);

  if (tot0 >= 1 && tot0 <= CAP && tot1 >= 1 && tot1 <= CAP) {
    int w0 = 0, w1 = 0;
#pragma unroll
    for (int j = 0; j < J; ++j) {
      if (x0[j] > th0) {
        sval[ws][0][base0 + w0] = x0[j];
        sidx[ws][0][base0 + w0] = (unsigned short)(lane + 64 * j);
        ++w0;
      }
      if (x1[j] > th1) {
        sval[ws][1][base1 + w1] = x1[j];
        sidx[ws][1][base1 + w1] = (unsigned short)(lane + 64 * j);
        ++w1;
      }
    }
    __threadfence_block();   // wave-local LDS visibility across lanes

    // -------- compacted half-wave solver from theta, validity-checked ---
    const float* svp = &sval[ws][half][0];
    int   tot_my = half ? tot1 : tot0;
    float tau_my = half ? th1  : th0;
    bool invalid = false, done = false;
    for (int it = 0; it < 24; ++it) {
      float a1 = 0.f, a2 = 0.f, cm = 0.f;
      for (int i = lane31; i < tot_my; i += 32) {
        float t = svp[i] - tau_my, r0 = fmaxf(t, 0.f);
        a1 += r0; a2 = fmaf(r0, r0, a2); cm += (t > 0.f) ? 1.f : 0.f;
      }
      float a1s = dpp_hscan_add(a1);
      float a2s = dpp_hscan_add(a2);
      float cms = dpp_hscan_add(cm);
      float s1 = half ? rlf(a1s, 63) : rlf(a1s, 31);
      float s2 = half ? rlf(a2s, 63) : rlf(a2s, 31);
      float cc = half ? rlf(cms, 63) : rlf(cms, 31);
      float f = s2 - 1.0f;
      if (it == 0 && f < -1e-6f) { invalid = true; done = true; }
      else if (!done) {
        if (f > 1e-6f && s1 > 1e-12f) tau_my += hstep(f, s1, cc);
        else done = true;
      }
      if (__ballot(done) == ~0ull) break;
    }
    bool inv0 = __builtin_amdgcn_readlane((int)invalid, 0)  != 0;
    bool inv1 = __builtin_amdgcn_readlane((int)invalid, 32) != 0;

    if (!inv0 && !inv1) {
      float tau0 = rlf(tau_my, 0);
      float tau1 = rlf(tau_my, 32);
      // -------- dense A write from live score registers (coalesced) ----
#pragma unroll
      for (int j = 0; j < J; ++j) {
        int kk = lane + 64 * j;
        float t0 = fmaxf(x0[j] - tau0, 0.f);
        float t1 = fmaxf(x1[j] - tau1, 0.f);
        arow[kk]        = t0 * t0;
        arow[LCOL + kk] = t1 * t1;
      }

      // -------- sparse P@V, half-wave split --------
      const unsigned short* sip = &sidx[ws][half][0];
      float acc[16];
#pragma unroll
      for (int d = 0; d < 16; ++d) acc[d] = 0.f;
      for (int i = lane31; i < tot_my; i += 32) {
        float t = svp[i] - tau_my;
        if (t > 0.f) {
          float p = t * t;
          int kk = sip[i];
          const float4* vp = (const float4*)(Vb + (size_t)kk * 16);
          float4 v0 = vp[0], v1 = vp[1], v2 = vp[2], v3 = vp[3];
          acc[0]  = fmaf(p, v0.x, acc[0]);  acc[1]  = fmaf(p, v0.y, acc[1]);
          acc[2]  = fmaf(p, v0.z, acc[2]);  acc[3]  = fmaf(p, v0.w, acc[3]);
          acc[4]  = fmaf(p, v1.x, acc[4]);  acc[5]  = fmaf(p, v1.y, acc[5]);
          acc[6]  = fmaf(p, v1.z, acc[6]);  acc[7]  = fmaf(p, v1.w, acc[7]);
          acc[8]  = fmaf(p, v2.x, acc[8]);  acc[9]  = fmaf(p, v2.y, acc[9]);
          acc[10] = fmaf(p, v2.z, acc[10]); acc[11] = fmaf(p, v2.w, acc[11]);
          acc[12] = fmaf(p, v3.x, acc[12]); acc[13] = fmaf(p, v3.y, acc[13]);
          acc[14] = fmaf(p, v3.z, acc[14]); acc[15] = fmaf(p, v3.w, acc[15]);
        }
      }
      float vv = 0.f;
#pragma unroll
      for (int d = 0; d < 16; ++d) {
        float sc = dpp_hscan_add(acc[d]);
        float td = half ? rlf(sc, 63) : rlf(sc, 31);
        vv = (lane31 == d) ? td : vv;
      }
      if (lane31 < 16) op[half * 128 + lane31] = vv;
      return;
    }
  }

  // ============ FALLBACK (rare): full dense solve from m-1, per row =====
#pragma unroll
  for (int pass = 0; pass < 2; ++pass) {
    float tau = (pass ? m1 : m0) - 1.0f;
    bool done = false;
    for (int it = 0; it < 24; ++it) {
      float a1l = 0.f, a2l = 0.f, acl = 0.f;
#pragma unroll
      for (int j = 0; j < J; ++j) {
        float xv = pass ? x1[j] : x0[j];
        float t = xv - tau, r0 = fmaxf(t, 0.f);
        a1l += r0; a2l = fmaf(r0, r0, a2l);
        acl += (t > 0.f) ? 1.f : 0.f;
      }
      float a1 = wave_sum(a1l);
      float a2 = wave_sum(a2l);
      float ac = wave_sum(acl);
      float f = a2 - 1.0f;
      bool g = !done && (f > 1e-6f) && (a1 > 1e-12f);
      if (g) tau += hstep(f, a1, ac); else done = true;
      if (done) break;
    }
    float acc[16];
#pragma unroll
    for (int d = 0; d < 16; ++d) acc[d] = 0.f;
#pragma unroll
    for (int j = 0; j < J; ++j) {
      int kk = lane + 64 * j;
      float xv = pass ? x1[j] : x0[j];
      float t = fmaxf(xv - tau, 0.f), p = t * t;
      arow[(size_t)pass * LCOL + kk] = p;
      const float4* vp = (const float4*)(Vb + (size_t)kk * 16);
      float4 v0 = vp[0], v1 = vp[1], v2 = vp[2], v3 = vp[3];
      acc[0]  = fmaf(p, v0.x, acc[0]);  acc[1]  = fmaf(p, v0.y, acc[1]);
      acc[2]  = fmaf(p, v0.z, acc[2]);  acc[3]  = fmaf(p, v0.w, acc[3]);
      acc[4]  = fmaf(p, v1.x, acc[4]);  acc[5]  = fmaf(p, v1.y, acc[5]);
      acc[6]  = fmaf(p, v1.z, acc[6]);  acc[7]  = fmaf(p, v1.w, acc[7]);
      acc[8]  = fmaf(p, v2.x, acc[8]);  acc[9]  = fmaf(p, v2.y, acc[9]);
      acc[10] = fmaf(p, v2.z, acc[10]); acc[11] = fmaf(p, v2.w, acc[11]);
      acc[12] = fmaf(p, v3.x, acc[12]); acc[13] = fmaf(p, v3.y, acc[13]);
      acc[14] = fmaf(p, v3.z, acc[14]); acc[15] = fmaf(p, v3.w, acc[15]);
    }
    float vv = 0.f;
#pragma unroll
    for (int d = 0; d < 16; ++d) {
      float tt = wave_bcast63(dpp_scan_add(acc[d]));
      vv = (lane == d) ? tt : vv;
    }
    if (lane < 16) op[pass * 128 + lane] = vv;
  }
}

// ---------------------------------------------------------------------------
// Fused: Y = X1 @ W1 + bias + X2 @ W2, then LayerNorm(gamma,beta) + ReLU.
// 4 rows per block, 128 threads (one output column each, 2 waves).
// ---------------------------------------------------------------------------
__global__ __launch_bounds__(128) void combine_ln_kernel(
    const float* __restrict__ X1, const float* __restrict__ X2,
    const float* __restrict__ W1, const float* __restrict__ W2,
    const float* __restrict__ bias, const float* __restrict__ gamma,
    const float* __restrict__ beta, float* __restrict__ O)
{
  __shared__ float x1s[4][128], x2s[4][128];
  __shared__ float red[2][8];
  int rb = blockIdx.x * 4;
  int c  = threadIdx.x;
#pragma unroll
  for (int i = 0; i < 4; ++i) {
    x1s[i][c] = X1[(size_t)(rb + i) * 128 + c];
    x2s[i][c] = X2[(size_t)(rb + i) * 128 + c];
  }
  __syncthreads();
  float b = bias[c];
  float a0 = b, a1 = b, a2 = b, a3 = b;
#pragma unroll 8
  for (int d = 0; d < 128; ++d) {
    float w1 = W1[d * 128 + c];
    float w2 = W2[d * 128 + c];
    a0 = fmaf(x1s[0][d], w1, fmaf(x2s[0][d], w2, a0));
    a1 = fmaf(x1s[1][d], w1, fmaf(x2s[1][d], w2, a1));
    a2 = fmaf(x1s[2][d], w1, fmaf(x2s[2][d], w2, a2));
    a3 = fmaf(x1s[3][d], w1, fmaf(x2s[3][d], w2, a3));
  }
  float s0 = wave_bcast63(dpp_scan_add(a0));
  float q0 = wave_bcast63(dpp_scan_add(a0 * a0));
  float s1 = wave_bcast63(dpp_scan_add(a1));
  float q1 = wave_bcast63(dpp_scan_add(a1 * a1));
  float s2 = wave_bcast63(dpp_scan_add(a2));
  float q2 = wave_bcast63(dpp_scan_add(a2 * a2));
  float s3 = wave_bcast63(dpp_scan_add(a3));
  float q3 = wave_bcast63(dpp_scan_add(a3 * a3));
  int wv = c >> 6;
  if ((c & 63) == 0) {
    red[wv][0] = s0; red[wv][1] = q0; red[wv][2] = s1; red[wv][3] = q1;
    red[wv][4] = s2; red[wv][5] = q2; red[wv][6] = s3; red[wv][7] = q3;
  }
  __syncthreads();
  float S0 = red[0][0] + red[1][0], Q0 = red[0][1] + red[1][1];
  float S1 = red[0][2] + red[1][2], Q1 = red[0][3] + red[1][3];
  float S2 = red[0][4] + red[1][4], Q2 = red[0][5] + red[1][5];
  float S3 = red[0][6] + red[1][6], Q3 = red[0][7] + red[1][7];
  float g = gamma[c], be = beta[c];
  float mu, var, rs;
  mu = S0 * (1.f / 128.f); var = fmaxf(Q0 * (1.f / 128.f) - mu * mu, 0.f);
  rs = rsqrtf(var + 1e-5f);
  O[(size_t)(rb + 0) * 128 + c] = fmaxf(fmaf((a0 - mu) * rs, g, be), 0.f);
  mu = S1 * (1.f / 128.f); var = fmaxf(Q1 * (1.f / 128.f) - mu * mu, 0.f);
  rs = rsqrtf(var + 1e-5f);
  O[(size_t)(rb + 1) * 128 + c] = fmaxf(fmaf((a1 - mu) * rs, g, be), 0.f);
  mu = S2 * (1.f / 128.f); var = fmaxf(Q2 * (1.f / 128.f) - mu * mu, 0.f);
  rs = rsqrtf(var + 1e-5f);
  O[(size_t)(rb + 2) * 128 + c] = fmaxf(fmaf((a2 - mu) * rs, g, be), 0.f);
  mu = S3 * (1.f / 128.f); var = fmaxf(Q3 * (1.f / 128.f) - mu * mu, 0.f);
  rs = rsqrtf(var + 1e-5f);
  O[(size_t)(rb + 3) * 128 + c] = fmaxf(fmaf((a3 - mu) * rs, g, be), 0.f);
}

// ---------------------------------------------------------------------------
extern "C"
__attribute__((visibility("default"), used))
void kernel_launch(void* const* d_in, const int* in_sizes, int n_in,
                   void* d_out, int out_size, void* d_ws, size_t ws_size,
                   hipStream_t stream)
{
  (void)in_sizes; (void)n_in; (void)out_size; (void)ws_size;
  const float* q     = (const float*)d_in[0];
  const float* k     = (const float*)d_in[1];
  const float* v     = (const float*)d_in[2];
  const float* v2    = (const float*)d_in[3];
  const float* W_Q   = (const float*)d_in[4];
  const float* b_Q   = (const float*)d_in[5];
  const float* W_K   = (const float*)d_in[6];
  const float* b_K   = (const float*)d_in[7];
  const float* W_V   = (const float*)d_in[8];
  const float* b_V   = (const float*)d_in[9];
  const float* W_V2  = (const float*)d_in[10];
  const float* b_V2  = (const float*)d_in[11];
  const float* W_O   = (const float*)d_in[12];
  const float* b_O   = (const float*)d_in[13];
  const float* W_O2  = (const float*)d_in[14];
  const float* b_O2  = (const float*)d_in[15];
  const float* W_R   = (const float*)d_in[16];
  const float* W_R2  = (const float*)d_in[17];
  const float* gamma = (const float*)d_in[18];
  const float* beta  = (const float*)d_in[19];

  char* ws = (char*)d_ws;
  const size_t MB = 1u << 20;
  float* Qp    = (float*)(ws + 0);        // chunk-major [bh][4][1024][4]
  float* Kp    = (float*)(ws + 2 * MB);   // chunk-major [bh][4][2048][4]
  float* Vp    = (float*)(ws + 6 * MB);   // row-major   [bh][2048][16]
  float* V2p   = (float*)(ws + 10 * MB);  // row-major   [bh][1024][16]
  float* outm1 = (float*)(ws + 12 * MB);
  float* outm2 = (float*)(ws + 14 * MB);

  float* out1  = (float*)d_out;              // (4,1024,128)
  float* out2  = out1 + (size_t)524288;      // (4,2048,128)
  float* Aout  = out1 + (size_t)1572864;     // (4,8,1024,2048)
  float* A2out = out1 + (size_t)68681728;    // (4,8,2048,1024)

  proj_all_kernel<<<6144, 128, 0, stream>>>(
      q, k, v, v2, W_Q, b_Q, W_K, b_K, W_V, b_V, W_V2, b_V2,
      Qp, Kp, Vp, V2p);

  attn_kernel<1024, 2048><<<4096, 256, 0, stream>>>(Qp, Kp, Vp,  Aout,  outm1);
  attn_kernel<2048, 1024><<<8192, 256, 0, stream>>>(Kp, Qp, V2p, A2out, outm2);

  combine_ln_kernel<<<1024, 128, 0, stream>>>(outm1, q, W_O,  W_R,  b_O,
                                              gamma, beta, out1);
  combine_ln_kernel<<<2048, 128, 0, stream>>>(outm2, k, W_O2, W_R2, b_O2,
                                              gamma, beta, out2);
}

// Round 9
// 1060.537 us; speedup vs baseline: 1.0338x; 1.0303x over previous
//
#include <hip/hip_runtime.h>

// ---------------------------------------------------------------------------
// All four projections in one launch. 4 rows per block, 128 threads.
// CHUNKED=0: Y[((bb*8+h)*L + l)*16 + dd]                      (row layout, V)
// CHUNKED=1: Y[(((bb*8+h)*4 + dd/4)*L + l)*4 + dd%4]   (chunk-major, Q and K)
// ---------------------------------------------------------------------------
__global__ __launch_bounds__(128) void proj_all_kernel(
    const float* __restrict__ q, const float* __restrict__ k,
    const float* __restrict__ v, const float* __restrict__ v2,
    const float* __restrict__ W_Q, const float* __restrict__ b_Q,
    const float* __restrict__ W_K, const float* __restrict__ b_K,
    const float* __restrict__ W_V, const float* __restrict__ b_V,
    const float* __restrict__ W_V2, const float* __restrict__ b_V2,
    float* __restrict__ Qp, float* __restrict__ Kp,
    float* __restrict__ Vp, float* __restrict__ V2p)
{
  __shared__ float xs[4][128];
  int blk = blockIdx.x;
  const float *X, *W, *B; float* Y; int L, chunked, rb;
  if (blk < 1024)      { X = q;  W = W_Q;  B = b_Q;  Y = Qp;  L = 1024; chunked = 1; rb = blk; }
  else if (blk < 3072) { X = k;  W = W_K;  B = b_K;  Y = Kp;  L = 2048; chunked = 1; rb = blk - 1024; }
  else if (blk < 5120) { X = v;  W = W_V;  B = b_V;  Y = Vp;  L = 2048; chunked = 0; rb = blk - 3072; }
  else                 { X = v2; W = W_V2; B = b_V2; Y = V2p; L = 1024; chunked = 0; rb = blk - 5120; }
  rb *= 4;
  int c = threadIdx.x;
#pragma unroll
  for (int i = 0; i < 4; ++i)
    xs[i][c] = X[(size_t)(rb + i) * 128 + c];
  __syncthreads();
  float b = B[c];
  float a0 = b, a1 = b, a2 = b, a3 = b;
#pragma unroll 8
  for (int d = 0; d < 128; ++d) {
    float w = W[d * 128 + c];
    a0 = fmaf(xs[0][d], w, a0);
    a1 = fmaf(xs[1][d], w, a1);
    a2 = fmaf(xs[2][d], w, a2);
    a3 = fmaf(xs[3][d], w, a3);
  }
  int h = c >> 4, dd = c & 15;
  float av[4] = { a0, a1, a2, a3 };
#pragma unroll
  for (int i = 0; i < 4; ++i) {
    int row = rb + i;
    int bb = row / L;
    int l  = row - bb * L;
    if (chunked)
      Y[(((size_t)(bb * 8 + h) * 4 + (dd >> 2)) * L + l) * 4 + (dd & 3)] = av[i];
    else
      Y[((size_t)(bb * 8 + h) * L + l) * 16 + dd] = av[i];
  }
}

// Guarded hybrid root step for f(u-shifted) = S2 - 1 over current support:
// exact segment root when discriminant real, else Newton.
static __device__ __forceinline__ float hstep(float f, float s1, float cnt)
{
  float arg = fmaf(-cnt, f, s1 * s1);
  return (arg > 0.f) ? f / (s1 + sqrtf(arg)) : f / (2.f * s1);
}

// ---------------------------------------------------------------------------
// Attention pass (fp32). ONE WAVE PER ROW (R5 structure, best measured).
// A-array stores are NON-TEMPORAL: A is write-once/never-read-by-us; nt
// avoids L2 write-allocate (R4 counters: FETCH 194MB / WRITE 592MB vs ~30 /
// ~270 ideal -> A lines were being fetched+rewritten through L2).
//
// FAST PATH (statistical threshold, verified): one pass gives row max m,
// mean mu, std sig. theta = max(mu + Z*sig, m-1) is a high-probability
// LOWER bound on tau*. Compact survivors {x > theta} DIRECTLY, run the
// monotone hybrid solver on the compacted set from theta. Iteration 0
// computes the true global f(theta); if f < -1e-6 (theta overshot), or
// count==0 or count>CAP, fall back to full dense solve from m-1.
// Accepted path: tau >= theta, excluded cols contribute exactly 0.
//
// No forced occupancy cap (round-3/4 lesson: min-waves below natural VGPR
// usage => scratch spill => GBs of HBM spill traffic).
// ---------------------------------------------------------------------------
template<int LROW, int LCOL>
__global__ __launch_bounds__(256) void attn_kernel(
    const float* __restrict__ RowM, const float* __restrict__ ColM,
    const float* __restrict__ ValM, float* __restrict__ Aout,
    float* __restrict__ OutWs)
{
  constexpr int J   = LCOL / 64;
  constexpr int CAP = 512;
  constexpr float Z = 1.0f;
  __shared__ float          sval[4][CAP];
  __shared__ unsigned short sidx[4][CAP];

  int ws   = threadIdx.x >> 6;                      // wave slot in block
  int wid  = blockIdx.x * 4 + ws;                   // global row id
  int lane = threadIdx.x & 63;
  int bh   = wid / LROW;
  int r    = wid - bh * LROW;
  int bb   = bh >> 3, h = bh & 7;

  float qf[16];
  { const float* qb = RowM + (size_t)bh * LROW * 16;   // chunk-major block
#pragma unroll
    for (int d = 0; d < 16; ++d)
      qf[d] = qb[((size_t)(d >> 2) * LROW + r) * 4 + (d & 3)] * 0.125f;
  }

  // -------- scores (raw) --------
  float x[J];
  const float4* Cb = (const float4*)(ColM + (size_t)bh * LCOL * 16);
#pragma unroll
  for (int j = 0; j < J; ++j) {
    int kk = lane + 64 * j;
    float4 k0 = Cb[0 * LCOL + kk];      // 16B/lane contiguous -> 1KB/wave
    float  s  = qf[0] * k0.x;
    s = fmaf(qf[1], k0.y, s); s = fmaf(qf[2], k0.z, s); s = fmaf(qf[3], k0.w, s);
    float4 k1 = Cb[1 * LCOL + kk];
    s = fmaf(qf[4], k1.x, s); s = fmaf(qf[5], k1.y, s);
    s = fmaf(qf[6], k1.z, s); s = fmaf(qf[7], k1.w, s);
    float4 k2 = Cb[2 * LCOL + kk];
    s = fmaf(qf[8], k2.x, s); s = fmaf(qf[9], k2.y, s);
    s = fmaf(qf[10], k2.z, s); s = fmaf(qf[11], k2.w, s);
    float4 k3 = Cb[3 * LCOL + kk];
    s = fmaf(qf[12], k3.x, s); s = fmaf(qf[13], k3.y, s);
    s = fmaf(qf[14], k3.z, s); s = fmaf(qf[15], k3.w, s);
    x[j] = s;
  }

  // -------- one-pass stats: max, sum, sumsq --------
  float m = -1e30f, sr = 0.f, qr = 0.f;
#pragma unroll
  for (int j = 0; j < J; ++j) {
    m = fmaxf(m, x[j]);
    sr += x[j];
    qr = fmaf(x[j], x[j], qr);
  }
#pragma unroll
  for (int off = 32; off >= 1; off >>= 1) {
    m  = fmaxf(m, __shfl_xor(m, off));
    sr += __shfl_xor(sr, off);
    qr += __shfl_xor(qr, off);
  }
  float mu  = sr * (1.f / (float)LCOL);
  float sig = sqrtf(fmaxf(qr * (1.f / (float)LCOL) - mu * mu, 0.f));
  float theta = fmaxf(fmaf(Z, sig, mu), m - 1.0f);

  float* arow = Aout + ((size_t)bh * LROW + r) * LCOL;
  const float* Vb = ValM + (size_t)bh * LCOL * 16;
  float* op = OutWs + ((size_t)bb * LROW + r) * 128 + h * 16;

  // -------- survivor count + compaction at theta --------
  int c = 0;
#pragma unroll
  for (int j = 0; j < J; ++j) c += (x[j] > theta) ? 1 : 0;
  int i = c;
#pragma unroll
  for (int off = 1; off <= 32; off <<= 1) {
    int t = __shfl_up(i, off);
    if (lane >= off) i += t;
  }
  int base = i - c;
  int tot  = __shfl(i, 63);

  if (tot >= 1 && tot <= CAP) {
    int w = 0;
#pragma unroll
    for (int j = 0; j < J; ++j) {
      if (x[j] > theta) {
        sval[ws][base + w] = x[j];
        sidx[ws][base + w] = (unsigned short)(lane + 64 * j);
        ++w;
      }
    }
    __threadfence_block();   // wave-local LDS visibility across lanes

    // -------- compacted monotone solver from theta, validity-checked ----
    float tau = theta;
    bool valid = true;
    for (int it = 0; it < 24; ++it) {
      float s1 = 0.f, s2 = 0.f;
      int cnt = 0;
      for (int i2 = lane; i2 < tot; i2 += 64) {
        float t = sval[ws][i2] - tau, r0 = fmaxf(t, 0.f);
        s1 += r0; s2 = fmaf(r0, r0, s2);
        cnt += __popcll(__ballot(t > 0.f));
      }
#pragma unroll
      for (int off = 32; off >= 1; off >>= 1) {
        s1 += __shfl_xor(s1, off);
        s2 += __shfl_xor(s2, off);
      }
      float f = s2 - 1.0f;
      if (it == 0 && f < -1e-6f) { valid = false; break; }  // theta > tau*
      if (f > 1e-6f && s1 > 1e-12f) tau += hstep(f, s1, (float)cnt);
      else break;                                           // converged
    }

    if (valid) {
      // -------- dense A write (non-temporal streaming stores) ----------
#pragma unroll
      for (int j = 0; j < J; ++j) {
        int kk = lane + 64 * j;
        float t = fmaxf(x[j] - tau, 0.f);
        __builtin_nontemporal_store(t * t, &arow[kk]);
      }

      // -------- sparse P@V over survivors --------
      float acc[16];
#pragma unroll
      for (int d = 0; d < 16; ++d) acc[d] = 0.f;
      for (int i2 = lane; i2 < tot; i2 += 64) {
        float t = sval[ws][i2] - tau;
        if (t > 0.f) {
          float p = t * t;
          int kk = sidx[ws][i2];
          const float4* vp = (const float4*)(Vb + (size_t)kk * 16);
          float4 v0 = vp[0], v1 = vp[1], v2 = vp[2], v3 = vp[3];
          acc[0]  = fmaf(p, v0.x, acc[0]);  acc[1]  = fmaf(p, v0.y, acc[1]);
          acc[2]  = fmaf(p, v0.z, acc[2]);  acc[3]  = fmaf(p, v0.w, acc[3]);
          acc[4]  = fmaf(p, v1.x, acc[4]);  acc[5]  = fmaf(p, v1.y, acc[5]);
          acc[6]  = fmaf(p, v1.z, acc[6]);  acc[7]  = fmaf(p, v1.w, acc[7]);
          acc[8]  = fmaf(p, v2.x, acc[8]);  acc[9]  = fmaf(p, v2.y, acc[9]);
          acc[10] = fmaf(p, v2.z, acc[10]); acc[11] = fmaf(p, v2.w, acc[11]);
          acc[12] = fmaf(p, v3.x, acc[12]); acc[13] = fmaf(p, v3.y, acc[13]);
          acc[14] = fmaf(p, v3.z, acc[14]); acc[15] = fmaf(p, v3.w, acc[15]);
        }
      }
#pragma unroll
      for (int off = 32; off >= 1; off >>= 1)
#pragma unroll
        for (int d = 0; d < 16; ++d) acc[d] += __shfl_xor(acc[d], off);
      float vv = acc[0];
#pragma unroll
      for (int d = 1; d < 16; ++d)
        vv = (lane == d) ? acc[d] : vv;
      if (lane < 16) op[lane] = vv;
      return;
    }
  }

  // ============ FALLBACK (rare): full dense solve from m-1 ==============
  float tau = m - 1.0f;
  bool done = false;
  for (int it = 0; it < 24; ++it) {
    float a1 = 0.f, a2 = 0.f;
    int ac = 0;
#pragma unroll
    for (int j = 0; j < J; ++j) {
      float t = x[j] - tau, r0 = fmaxf(t, 0.f);
      a1 += r0; a2 = fmaf(r0, r0, a2);
      ac += __popcll(__ballot(t > 0.f));
    }
#pragma unroll
    for (int off = 32; off >= 1; off >>= 1) {
      a1 += __shfl_xor(a1, off);
      a2 += __shfl_xor(a2, off);
    }
    float f = a2 - 1.0f;
    bool g = !done && (f > 1e-6f) && (a1 > 1e-12f);
    if (g) tau += hstep(f, a1, (float)ac); else done = true;
    if (done) break;
  }

  float acc[16];
#pragma unroll
  for (int d = 0; d < 16; ++d) acc[d] = 0.f;
#pragma unroll
  for (int j = 0; j < J; ++j) {
    int kk = lane + 64 * j;
    float t = fmaxf(x[j] - tau, 0.f), p = t * t;
    __builtin_nontemporal_store(p, &arow[kk]);
    const float4* vp = (const float4*)(Vb + (size_t)kk * 16);
    float4 v0 = vp[0], v1 = vp[1], v2 = vp[2], v3 = vp[3];
    acc[0]  = fmaf(p, v0.x, acc[0]);  acc[1]  = fmaf(p, v0.y, acc[1]);
    acc[2]  = fmaf(p, v0.z, acc[2]);  acc[3]  = fmaf(p, v0.w, acc[3]);
    acc[4]  = fmaf(p, v1.x, acc[4]);  acc[5]  = fmaf(p, v1.y, acc[5]);
    acc[6]  = fmaf(p, v1.z, acc[6]);  acc[7]  = fmaf(p, v1.w, acc[7]);
    acc[8]  = fmaf(p, v2.x, acc[8]);  acc[9]  = fmaf(p, v2.y, acc[9]);
    acc[10] = fmaf(p, v2.z, acc[10]); acc[11] = fmaf(p, v2.w, acc[11]);
    acc[12] = fmaf(p, v3.x, acc[12]); acc[13] = fmaf(p, v3.y, acc[13]);
    acc[14] = fmaf(p, v3.z, acc[14]); acc[15] = fmaf(p, v3.w, acc[15]);
  }
#pragma unroll
  for (int off = 32; off >= 1; off >>= 1)
#pragma unroll
    for (int d = 0; d < 16; ++d) acc[d] += __shfl_xor(acc[d], off);
  float vv = acc[0];
#pragma unroll
  for (int d = 1; d < 16; ++d)
    vv = (lane == d) ? acc[d] : vv;
  if (lane < 16) op[lane] = vv;
}

// ---------------------------------------------------------------------------
// Fused: Y = X1 @ W1 + bias + X2 @ W2, then LayerNorm(gamma,beta) + ReLU.
// 4 rows per block, 128 threads (one output column each, 2 waves).
// ---------------------------------------------------------------------------
__global__ __launch_bounds__(128) void combine_ln_kernel(
    const float* __restrict__ X1, const float* __restrict__ X2,
    const float* __restrict__ W1, const float* __restrict__ W2,
    const float* __restrict__ bias, const float* __restrict__ gamma,
    const float* __restrict__ beta, float* __restrict__ O)
{
  __shared__ float x1s[4][128], x2s[4][128];
  __shared__ float red[2][8];
  int rb = blockIdx.x * 4;
  int c  = threadIdx.x;
#pragma unroll
  for (int i = 0; i < 4; ++i) {
    x1s[i][c] = X1[(size_t)(rb + i) * 128 + c];
    x2s[i][c] = X2[(size_t)(rb + i) * 128 + c];
  }
  __syncthreads();
  float b = bias[c];
  float a0 = b, a1 = b, a2 = b, a3 = b;
#pragma unroll 8
  for (int d = 0; d < 128; ++d) {
    float w1 = W1[d * 128 + c];
    float w2 = W2[d * 128 + c];
    a0 = fmaf(x1s[0][d], w1, fmaf(x2s[0][d], w2, a0));
    a1 = fmaf(x1s[1][d], w1, fmaf(x2s[1][d], w2, a1));
    a2 = fmaf(x1s[2][d], w1, fmaf(x2s[2][d], w2, a2));
    a3 = fmaf(x1s[3][d], w1, fmaf(x2s[3][d], w2, a3));
  }
  float s0 = a0, s1 = a1, s2 = a2, s3 = a3;
  float q0 = a0 * a0, q1 = a1 * a1, q2 = a2 * a2, q3 = a3 * a3;
#pragma unroll
  for (int off = 32; off >= 1; off >>= 1) {
    s0 += __shfl_xor(s0, off); q0 += __shfl_xor(q0, off);
    s1 += __shfl_xor(s1, off); q1 += __shfl_xor(q1, off);
    s2 += __shfl_xor(s2, off); q2 += __shfl_xor(q2, off);
    s3 += __shfl_xor(s3, off); q3 += __shfl_xor(q3, off);
  }
  int wv = c >> 6;
  if ((c & 63) == 0) {
    red[wv][0] = s0; red[wv][1] = q0; red[wv][2] = s1; red[wv][3] = q1;
    red[wv][4] = s2; red[wv][5] = q2; red[wv][6] = s3; red[wv][7] = q3;
  }
  __syncthreads();
  float S0 = red[0][0] + red[1][0], Q0 = red[0][1] + red[1][1];
  float S1 = red[0][2] + red[1][2], Q1 = red[0][3] + red[1][3];
  float S2 = red[0][4] + red[1][4], Q2 = red[0][5] + red[1][5];
  float S3 = red[0][6] + red[1][6], Q3 = red[0][7] + red[1][7];
  float g = gamma[c], be = beta[c];
  float mu, var, rs;
  mu = S0 * (1.f / 128.f); var = fmaxf(Q0 * (1.f / 128.f) - mu * mu, 0.f);
  rs = rsqrtf(var + 1e-5f);
  O[(size_t)(rb + 0) * 128 + c] = fmaxf(fmaf((a0 - mu) * rs, g, be), 0.f);
  mu = S1 * (1.f / 128.f); var = fmaxf(Q1 * (1.f / 128.f) - mu * mu, 0.f);
  rs = rsqrtf(var + 1e-5f);
  O[(size_t)(rb + 1) * 128 + c] = fmaxf(fmaf((a1 - mu) * rs, g, be), 0.f);
  mu = S2 * (1.f / 128.f); var = fmaxf(Q2 * (1.f / 128.f) - mu * mu, 0.f);
  rs = rsqrtf(var + 1e-5f);
  O[(size_t)(rb + 2) * 128 + c] = fmaxf(fmaf((a2 - mu) * rs, g, be), 0.f);
  mu = S3 * (1.f / 128.f); var = fmaxf(Q3 * (1.f / 128.f) - mu * mu, 0.f);
  rs = rsqrtf(var + 1e-5f);
  O[(size_t)(rb + 3) * 128 + c] = fmaxf(fmaf((a3 - mu) * rs, g, be), 0.f);
}

// ---------------------------------------------------------------------------
extern "C"
__attribute__((visibility("default"), used))
void kernel_launch(void* const* d_in, const int* in_sizes, int n_in,
                   void* d_out, int out_size, void* d_ws, size_t ws_size,
                   hipStream_t stream)
{
  (void)in_sizes; (void)n_in; (void)out_size; (void)ws_size;
  const float* q     = (const float*)d_in[0];
  const float* k     = (const float*)d_in[1];
  const float* v     = (const float*)d_in[2];
  const float* v2    = (const float*)d_in[3];
  const float* W_Q   = (const float*)d_in[4];
  const float* b_Q   = (const float*)d_in[5];
  const float* W_K   = (const float*)d_in[6];
  const float* b_K   = (const float*)d_in[7];
  const float* W_V   = (const float*)d_in[8];
  const float* b_V   = (const float*)d_in[9];
  const float* W_V2  = (const float*)d_in[10];
  const float* b_V2  = (const float*)d_in[11];
  const float* W_O   = (const float*)d_in[12];
  const float* b_O   = (const float*)d_in[13];
  const float* W_O2  = (const float*)d_in[14];
  const float* b_O2  = (const float*)d_in[15];
  const float* W_R   = (const float*)d_in[16];
  const float* W_R2  = (const float*)d_in[17];
  const float* gamma = (const float*)d_in[18];
  const float* beta  = (const float*)d_in[19];

  char* ws = (char*)d_ws;
  const size_t MB = 1u << 20;
  float* Qp    = (float*)(ws + 0);        // chunk-major [bh][4][1024][4]
  float* Kp    = (float*)(ws + 2 * MB);   // chunk-major [bh][4][2048][4]
  float* Vp    = (float*)(ws + 6 * MB);   // row-major   [bh][2048][16]
  float* V2p   = (float*)(ws + 10 * MB);  // row-major   [bh][1024][16]
  float* outm1 = (float*)(ws + 12 * MB);
  float* outm2 = (float*)(ws + 14 * MB);

  float* out1  = (float*)d_out;              // (4,1024,128)
  float* out2  = out1 + (size_t)524288;      // (4,2048,128)
  float* Aout  = out1 + (size_t)1572864;     // (4,8,1024,2048)
  float* A2out = out1 + (size_t)68681728;    // (4,8,2048,1024)

  proj_all_kernel<<<6144, 128, 0, stream>>>(
      q, k, v, v2, W_Q, b_Q, W_K, b_K, W_V, b_V, W_V2, b_V2,
      Qp, Kp, Vp, V2p);

  attn_kernel<1024, 2048><<<8192,  256, 0, stream>>>(Qp, Kp, Vp,  Aout,  outm1);
  attn_kernel<2048, 1024><<<16384, 256, 0, stream>>>(Kp, Qp, V2p, A2out, outm2);

  combine_ln_kernel<<<1024, 128, 0, stream>>>(outm1, q, W_O,  W_R,  b_O,
                                              gamma, beta, out1);
  combine_ln_kernel<<<2048, 128, 0, stream>>>(outm2, k, W_O2, W_R2, b_O2,
                                              gamma, beta, out2);
}